// Round 5
// baseline (238.078 us; speedup 1.0000x reference)
//
#include <hip/hip_runtime.h>
#include <stdint.h>

#define B_ 4
#define S_ 2048
#define E_ 1024
#define D_ 1024   // attention dim

typedef short  bf16x8 __attribute__((ext_vector_type(8)));
typedef float  f32x4  __attribute__((ext_vector_type(4)));

// fp32 -> bf16 round-to-nearest-even
static __device__ __forceinline__ unsigned short f2bf(float f) {
    unsigned int u = __float_as_uint(f);
    u += 0x7fffu + ((u >> 16) & 1u);
    return (unsigned short)(u >> 16);
}

// async global->LDS, 16B per lane. LDS dest = wave-uniform base + lane*16.
static __device__ __forceinline__ void async16(const unsigned short* g, unsigned short* l) {
    auto gp = (const __attribute__((address_space(1))) void*)(uintptr_t)g;
    auto lp = (__attribute__((address_space(3))) void*)(uintptr_t)l;
    __builtin_amdgcn_global_load_lds(gp, lp, 16, 0, 0);
}

// ---------------------------------------------------------------------------
// LDS sub-tile unit (BK=64): row = 128 B = 8 chunks of 16 B. XOR swizzle:
// global chunk q of row r -> LDS chunk q^(r&7). One async16 covers 8 rows:
// lane l -> row +(l>>3), global chunk (l&7)^(l>>3). Reader k-half s reads
// chunk (s*4+quad)^(r&7). Conflict-free (SQ_LDS_BANK_CONFLICT=0, measured).
//
// R5: proj ported to the 8-phase-class 256^2 deep pipeline (learn_hip m198/
// m201: 912->1167/1563 TF on this exact baseline structure). Geometry:
// BM=BN=256, BK=64, 512 thr (8 waves 2Mx4N), LDS 128 KB dbuf, 1 block/CU.
// Per K-tile: 4 quadrant-phases, each {2 async16 (kt+1) || 12 ds_read_b128 ||
// setprio(1) 16-MFMA setprio(0) || raw s_barrier}. Loads stay in flight
// across the 3 raw phase barriers (counted-vmcnt effect); the only full
// drain is the iter-end __syncthreads(). Correctness does NOT depend on the
// raw barriers: within an iter, buf c is read-only and async16 writes go to
// buf c^1 (disjoint); all cross-buffer hazards separated by __syncthreads().
// Grid: M=8192 x N=3072 (K|Q|V concat) = 32x12 = 384 blocks, XCD-bijective
// swizzle (384 = 8x48). exp/pv/convert unchanged from R4.
// ---------------------------------------------------------------------------

// Kernel 0: fp32 -> bf16 convert (x -> xb, [Wk;Wq;Wv] -> Wb). Grid-stride.
__global__ __launch_bounds__(256)
void convert_kernel(const float* __restrict__ x,  const float* __restrict__ Wk,
                    const float* __restrict__ Wq, const float* __restrict__ Wv,
                    unsigned short* __restrict__ xb, unsigned short* __restrict__ Wb)
{
    const long long total  = (long long)B_ * S_ * E_ + 3LL * D_ * E_;  // 11534336
    const long long stride = (long long)gridDim.x * 256 * 4;
    for (long long idx = ((long long)blockIdx.x * 256 + threadIdx.x) * 4;
         idx < total; idx += stride) {
        const float* src; unsigned short* dst; long long off;
        if (idx < (long long)B_ * S_ * E_) {
            src = x; dst = xb; off = idx;
        } else {
            long long w = idx - (long long)B_ * S_ * E_;
            const int sel = (int)(w >> 20);          // 2^20 elems per W
            off = w & 1048575LL;
            src = (sel == 0) ? Wk : (sel == 1) ? Wq : Wv;
            dst = Wb + ((long long)sel << 20);
        }
        const float4 f = *(const float4*)(src + off);
        ushort4 u = { f2bf(f.x), f2bf(f.y), f2bf(f.z), f2bf(f.w) };
        *(ushort4*)(dst + off) = u;
    }
}

// ---------------------------------------------------------------------------
// Kernel 1: projections, 256^2 deep-pipelined (see header comment).
// C[m,n] = sum_e xb[m,e]*Wb[n,e]; n<1024 -> K, <2048 -> Q (x 1/32), else V
// (transposed store to Vt). Dynamic LDS: 131072 B.
// ---------------------------------------------------------------------------
__global__ __launch_bounds__(512, 2)
void proj_kernel(const unsigned short* __restrict__ xb,
                 const unsigned short* __restrict__ Wb,
                 unsigned short* __restrict__ Qb,
                 unsigned short* __restrict__ Kb,
                 unsigned short* __restrict__ Vt)
{
    extern __shared__ __align__(16) unsigned short lds[];
    // layout (elems): A0 [0,16384) A1 [16384,32768) B0 [32768,49152) B1 [49152,65536)

    // XCD-bijective swizzle: 384 blocks = 8 XCDs x 48 contiguous
    const int bid = blockIdx.x;
    const int swz = (bid & 7) * 48 + (bid >> 3);
    const int my  = swz / 12;              // 0..31
    const int ny  = swz - my * 12;         // 0..11
    const int m0  = my * 256;
    const int wsel = ny >> 2;              // 0=K, 1=Q, 2=V
    const int nloc = (ny & 3) * 256;

    const int t = threadIdx.x;
    const int lane = t & 63, wave = t >> 6;        // 8 waves
    const int l15 = lane & 15, quad = lane >> 4;
    const int wm2 = wave & 1, wn4 = wave >> 1;     // 2M x 4N wave grid
    const int lr = lane >> 3;                      // staging row-in-unit
    const int lc = ((lane & 7) ^ lr) * 8;          // staging k-col (elems)
    const int l7 = l15 & 7;

    // staging bases (include per-lane terms; async16 source is per-lane)
    const unsigned short* gAb = xb + (size_t)(m0 + lr) * E_ + lc;
    const unsigned short* gBb = Wb + (size_t)(ny * 256 + lr) * E_ + lc;

    f32x4 acc[8][4];
    #pragma unroll
    for (int i = 0; i < 8; i++)
        #pragma unroll
        for (int j = 0; j < 4; j++) acc[i][j] = {0.f, 0.f, 0.f, 0.f};

    // prologue: stage kt=0 into buf 0. waves 0-3 -> A units 0..31, 4-7 -> B.
    #pragma unroll
    for (int i = 0; i < 8; i++) {
        const int u = wave * 8 + i;
        if (u < 32) async16(gAb + (size_t)(u * 8) * E_,        lds +         u * 512);
        else        async16(gBb + (size_t)((u - 32) * 8) * E_, lds + 32768 + (u - 32) * 512);
    }
    __syncthreads();   // full drain: buf0 ready

    for (int kt = 0; kt < 16; kt++) {
        const int c = kt & 1;
        const unsigned short* Ac = lds + c * 16384;
        const unsigned short* Bc = lds + 32768 + c * 16384;
        unsigned short* An = lds + (c ^ 1) * 16384;
        unsigned short* Bn = lds + 32768 + (c ^ 1) * 16384;

        #pragma unroll
        for (int p = 0; p < 4; p++) {
            // stage 2 units of K-tile kt+1 into the other buffer
            if (kt < 15) {
                const int k0 = (kt + 1) * 64;
                #pragma unroll
                for (int i = 0; i < 2; i++) {
                    const int u = wave * 8 + p * 2 + i;
                    if (u < 32) async16(gAb + (size_t)(u * 8) * E_ + k0,        An +        u * 512);
                    else        async16(gBb + (size_t)((u - 32) * 8) * E_ + k0, Bn + (u - 32) * 512);
                }
            }
            const int mh = p >> 1, nh = p & 1;     // quadrant
            bf16x8 af[2][4], bfr[2][2];
            #pragma unroll
            for (int s = 0; s < 2; s++) {
                const int cs = ((s * 4 + quad) ^ l7) * 8;
                #pragma unroll
                for (int ii = 0; ii < 4; ii++) {
                    const int r = wm2 * 128 + (mh * 4 + ii) * 16 + l15;
                    af[s][ii] = *(const bf16x8*)&Ac[r * 64 + cs];
                }
                #pragma unroll
                for (int jj = 0; jj < 2; jj++) {
                    const int r = wn4 * 64 + (nh * 2 + jj) * 16 + l15;
                    bfr[s][jj] = *(const bf16x8*)&Bc[r * 64 + cs];
                }
            }
            __builtin_amdgcn_s_setprio(1);
            #pragma unroll
            for (int s = 0; s < 2; s++)
                #pragma unroll
                for (int ii = 0; ii < 4; ii++)
                    #pragma unroll
                    for (int jj = 0; jj < 2; jj++)
                        acc[mh * 4 + ii][nh * 2 + jj] =
                            __builtin_amdgcn_mfma_f32_16x16x32_bf16(
                                af[s][ii], bfr[s][jj], acc[mh * 4 + ii][nh * 2 + jj], 0, 0, 0);
            __builtin_amdgcn_s_setprio(0);
            if (p < 3) __builtin_amdgcn_s_barrier();   // pacing only
        }
        __syncthreads();   // drains vmcnt: buf c^1 complete; buf c free to overwrite
    }

    // epilogue: wave (wm2,wn4) owns rows m0+wm2*128+[0,128), cols nloc+wn4*64+[0,64)
    if (wsel == 0) {
        #pragma unroll
        for (int i = 0; i < 8; i++)
            #pragma unroll
            for (int j = 0; j < 4; j++) {
                const int gn = nloc + wn4 * 64 + j * 16 + l15;
                #pragma unroll
                for (int r = 0; r < 4; r++) {
                    const int gm = m0 + wm2 * 128 + i * 16 + quad * 4 + r;
                    Kb[(size_t)gm * D_ + gn] = f2bf(acc[i][j][r]);
                }
            }
    } else if (wsel == 1) {
        #pragma unroll
        for (int i = 0; i < 8; i++)
            #pragma unroll
            for (int j = 0; j < 4; j++) {
                const int gn = nloc + wn4 * 64 + j * 16 + l15;
                #pragma unroll
                for (int r = 0; r < 4; r++) {
                    const int gm = m0 + wm2 * 128 + i * 16 + quad * 4 + r;
                    Qb[(size_t)gm * D_ + gn] = f2bf(acc[i][j][r] * 0.03125f);
                }
            }
    } else {
        #pragma unroll
        for (int i = 0; i < 8; i++)
            #pragma unroll
            for (int j = 0; j < 4; j++) {
                const int s0 = m0 + wm2 * 128 + i * 16 + quad * 4;
                const int b  = s0 >> 11, sl = s0 & (S_ - 1);
                const int gn = nloc + wn4 * 64 + j * 16 + l15;
                ushort4 u = { f2bf(acc[i][j][0]), f2bf(acc[i][j][1]),
                              f2bf(acc[i][j][2]), f2bf(acc[i][j][3]) };
                *(ushort4*)&Vt[((size_t)(b << 10) + gn) * S_ + sl] = u;
            }
    }
}

// ---------------------------------------------------------------------------
// Kernel 2: E = exp(Qs K^T), causal, bf16 -> P. 128x128 tile, BK=64,
// single-buffered 32 KB LDS. COMPACT grid (136 tri-tiles, B): heavy-first
// enumeration (mt=15 first), no dud blocks. Scores bounded (|s| ~< 2).
// rowpart[b][nt*2+wn][row].
// ---------------------------------------------------------------------------
__global__ __launch_bounds__(256, 4)
void expscores_kernel(const unsigned short* __restrict__ Qb,
                      const unsigned short* __restrict__ Kb,
                      unsigned short* __restrict__ P,
                      float* __restrict__ rowpart)
{
    int rem = blockIdx.x;
    int mt = 15, cnt = 16;
    while (rem >= cnt) { rem -= cnt; mt--; cnt--; }
    const int nt = rem;
    const int b  = blockIdx.y;

    __shared__ __align__(16) unsigned short As[128 * 64];
    __shared__ __align__(16) unsigned short Bs[128 * 64];

    const int t = threadIdx.x;
    const int m0 = mt * 128, n0 = nt * 128;

    const int lane = t & 63, wave = t >> 6;
    const int l15 = lane & 15, quad = lane >> 4;
    const int wm = wave & 1, wn = wave >> 1;
    const int sr = lane >> 3;
    const int sq = ((lane & 7) ^ sr) * 8;
    const int l7 = l15 & 7;

    const unsigned short* gA = Qb + (size_t)b * S_ * D_ + (size_t)(m0 + wave * 32 + sr) * D_ + sq;
    const unsigned short* gB = Kb + (size_t)b * S_ * D_ + (size_t)(n0 + wave * 32 + sr) * D_ + sq;
    unsigned short* lA = &As[wave * 2048];
    unsigned short* lB = &Bs[wave * 2048];

    f32x4 acc[4][4];
    #pragma unroll
    for (int i = 0; i < 4; i++)
        #pragma unroll
        for (int j = 0; j < 4; j++) acc[i][j] = {0.f, 0.f, 0.f, 0.f};

    for (int kt = 0; kt < 16; kt++) {
        const int k0 = kt * 64;
        __syncthreads();
        #pragma unroll
        for (int i = 0; i < 4; i++) {
            async16(gA + k0 + i * 8 * D_, lA + i * 512);
            async16(gB + k0 + i * 8 * D_, lB + i * 512);
        }
        __syncthreads();

        #pragma unroll
        for (int s = 0; s < 2; s++) {
            const int cs = ((s * 4 + quad) ^ l7) * 8;
            bf16x8 af[4], bfr[4];
            #pragma unroll
            for (int i = 0; i < 4; i++)
                af[i] = *(const bf16x8*)&As[(wm * 64 + i * 16 + l15) * 64 + cs];
            #pragma unroll
            for (int j = 0; j < 4; j++)
                bfr[j] = *(const bf16x8*)&Bs[(wn * 64 + j * 16 + l15) * 64 + cs];
            #pragma unroll
            for (int i = 0; i < 4; i++)
                #pragma unroll
                for (int j = 0; j < 4; j++)
                    acc[i][j] = __builtin_amdgcn_mfma_f32_16x16x32_bf16(af[i], bfr[j], acc[i][j], 0, 0, 0);
        }
    }

    unsigned short* Pb = P + (size_t)b * S_ * S_;
    #pragma unroll
    for (int i = 0; i < 4; i++)
        #pragma unroll
        for (int j = 0; j < 4; j++) {
            const int gn = n0 + wn * 64 + j * 16 + l15;
            #pragma unroll
            for (int r = 0; r < 4; r++) {
                const int gm = m0 + wm * 64 + i * 16 + quad * 4 + r;
                const float e = (gn <= gm) ? __expf(acc[i][j][r]) : 0.f;
                acc[i][j][r] = e;
                Pb[(size_t)gm * S_ + gn] = f2bf(e);
            }
        }

    float* rp = rowpart + ((size_t)b * 32 + nt * 2 + wn) * S_;
    #pragma unroll
    for (int i = 0; i < 4; i++) {
        float rsub[4];
        #pragma unroll
        for (int r = 0; r < 4; r++) {
            float s = acc[i][0][r] + acc[i][1][r] + acc[i][2][r] + acc[i][3][r];
            #pragma unroll
            for (int off = 8; off; off >>= 1) s += __shfl_xor(s, off);
            rsub[r] = s;
        }
        if (l15 == 0) {
            #pragma unroll
            for (int r = 0; r < 4; r++)
                rp[m0 + wm * 64 + i * 16 + quad * 4 + r] = rsub[r];
        }
    }
}

// ---------------------------------------------------------------------------
// Kernel 3: out = (E @ V) / rowsum. 128x128 tile, BK=64, DOUBLE-BUFFERED
// (LDS 64 KB, 2 blocks/CU). Grid (8 nt FAST, 16 y, B); mt = (b&2)?y:15-y so
// co-resident pairs have complementary iteration counts -> uniform 36
// iters/CU. rowsum gather hoisted before the K-loop.
// ---------------------------------------------------------------------------
__global__ __launch_bounds__(256, 2)
void pv_kernel(const unsigned short* __restrict__ P,
               const unsigned short* __restrict__ Vt,
               const float* __restrict__ rowpart,
               float* __restrict__ out)
{
    const int nt = blockIdx.x;
    const int yy = blockIdx.y;
    const int b  = blockIdx.z;
    const int mt = (b & 2) ? yy : (15 - yy);  // complementary pairing across b

    __shared__ __align__(16) unsigned short As[2 * 128 * 64];
    __shared__ __align__(16) unsigned short Bs[2 * 128 * 64];

    const int t = threadIdx.x;
    const int m0 = mt * 128, n0 = nt * 128;
    const int niter = 2 * mt + 2;             // kend = m0+128, BK=64

    const int lane = t & 63, wave = t >> 6;
    const int l15 = lane & 15, quad = lane >> 4;
    const int wm = wave & 1, wn = wave >> 1;
    const int sr = lane >> 3;
    const int sq = ((lane & 7) ^ sr) * 8;
    const int l7 = l15 & 7;

    const unsigned short* gA = P  + (size_t)b * S_ * S_ + (size_t)(m0 + wave * 32 + sr) * S_ + sq;
    const unsigned short* gB = Vt + (size_t)b * D_ * S_ + (size_t)(n0 + wave * 32 + sr) * S_ + sq;
    unsigned short* lA = &As[wave * 2048];
    unsigned short* lB = &Bs[wave * 2048];

    // 1/rowsum gather issued before the K-loop (hides under prologue staging)
    const float* rp = rowpart + (size_t)b * 32 * S_ + (m0 + wm * 64 + lane);
    float rsum = 0.f;
    for (int k = 0; k < niter; k++) rsum += rp[(size_t)k * S_];
    const float invr = 1.0f / rsum;

    f32x4 acc[4][4];
    #pragma unroll
    for (int i = 0; i < 4; i++)
        #pragma unroll
        for (int j = 0; j < 4; j++) acc[i][j] = {0.f, 0.f, 0.f, 0.f};

    // prologue: stage k=0 into buffer 0
    #pragma unroll
    for (int i = 0; i < 4; i++) {
        async16(gA + i * 8 * S_, lA + i * 512);
        async16(gB + i * 8 * S_, lB + i * 512);
    }

    int buf = 0;
    for (int kt = 0; kt < niter; kt++) {
        __syncthreads();
        if (kt + 1 < niter) {
            const int k0 = (kt + 1) * 64;
            const int nb = (buf ^ 1) * 8192;
            #pragma unroll
            for (int i = 0; i < 4; i++) {
                async16(gA + k0 + i * 8 * S_, lA + nb + i * 512);
                async16(gB + k0 + i * 8 * S_, lB + nb + i * 512);
            }
        }
        const unsigned short* Ac = As + buf * 8192;
        const unsigned short* Bc = Bs + buf * 8192;
        #pragma unroll
        for (int s = 0; s < 2; s++) {
            const int cs = ((s * 4 + quad) ^ l7) * 8;
            bf16x8 af[4], bfr[4];
            #pragma unroll
            for (int i = 0; i < 4; i++)
                af[i] = *(const bf16x8*)&Ac[(wm * 64 + i * 16 + l15) * 64 + cs];
            #pragma unroll
            for (int j = 0; j < 4; j++)
                bfr[j] = *(const bf16x8*)&Bc[(wn * 64 + j * 16 + l15) * 64 + cs];
            #pragma unroll
            for (int i = 0; i < 4; i++)
                #pragma unroll
                for (int j = 0; j < 4; j++)
                    acc[i][j] = __builtin_amdgcn_mfma_f32_16x16x32_bf16(af[i], bfr[j], acc[i][j], 0, 0, 0);
        }
        buf ^= 1;
    }

    #pragma unroll
    for (int i = 0; i < 4; i++) {
        #pragma unroll
        for (int r = 0; r < 4; r++) {
            const float vr = __shfl(invr, i * 16 + quad * 4 + r);
            const int gm = m0 + wm * 64 + i * 16 + quad * 4 + r;
            #pragma unroll
            for (int j = 0; j < 4; j++) {
                const int gn = n0 + wn * 64 + j * 16 + l15;
                out[((size_t)b * S_ + gm) * D_ + gn] = rintf(acc[i][j][r] * vr * 1e4f) * 1e-4f;
            }
        }
    }
}

// ---------------------------------------------------------------------------
// Workspace (~85 MB):
//   [0,     16.7M)  Qb bf16 [4][2048][1024]
//   [16.7M, 33.5M)  Kb bf16
//   [33.5M, 50.3M)  Vt bf16 [4][1024][2048]
//   [50.3M, 83.9M)  P  bf16 [4][2048][2048]
//       xb (16.7M) + Wb (6.3M) overlay the start of P's region (dead before
//       expscores writes P).
//   [83.9M, +1M)    rowpart fp32 [4][32][2048]
// ---------------------------------------------------------------------------
extern "C" void kernel_launch(void* const* d_in, const int* in_sizes, int n_in,
                              void* d_out, int out_size, void* d_ws, size_t ws_size,
                              hipStream_t stream)
{
    (void)in_sizes; (void)n_in; (void)out_size; (void)ws_size;
    const float* x  = (const float*)d_in[0];
    const float* Wk = (const float*)d_in[1];
    const float* Wq = (const float*)d_in[2];
    const float* Wv = (const float*)d_in[3];
    float* out = (float*)d_out;

    char* ws = (char*)d_ws;
    unsigned short* Qb = (unsigned short*)ws;
    unsigned short* Kb = Qb + (size_t)B_ * S_ * D_;
    unsigned short* Vt = Kb + (size_t)B_ * S_ * D_;
    unsigned short* P  = Vt + (size_t)B_ * D_ * S_;
    unsigned short* xb = P;                                  // overlay (dead early)
    unsigned short* Wb = xb + (size_t)B_ * S_ * E_;
    float* rowpart = (float*)(P + (size_t)B_ * S_ * S_);

    convert_kernel  <<<2048, 256, 0, stream>>>(x, Wk, Wq, Wv, xb, Wb);
    proj_kernel     <<<dim3(384, 1, 1), 512, 131072, stream>>>(xb, Wb, Qb, Kb, Vt);
    expscores_kernel<<<dim3(136, B_, 1), 256, 0, stream>>>(Qb, Kb, P, rowpart);
    pv_kernel       <<<dim3(8, 16, B_),  256, 0, stream>>>(P, Vt, rowpart, out);
}

// Round 6
// 219.769 us; speedup vs baseline: 1.0833x; 1.0833x over previous
//
#include <hip/hip_runtime.h>
#include <stdint.h>

#define B_ 4
#define S_ 2048
#define E_ 1024
#define D_ 1024   // attention dim

typedef short  bf16x8 __attribute__((ext_vector_type(8)));
typedef float  f32x4  __attribute__((ext_vector_type(4)));

// fp32 -> bf16 round-to-nearest-even
static __device__ __forceinline__ unsigned short f2bf(float f) {
    unsigned int u = __float_as_uint(f);
    u += 0x7fffu + ((u >> 16) & 1u);
    return (unsigned short)(u >> 16);
}

// async global->LDS, 16B per lane. LDS dest = wave-uniform base + lane*16.
static __device__ __forceinline__ void async16(const unsigned short* g, unsigned short* l) {
    auto gp = (const __attribute__((address_space(1))) void*)(uintptr_t)g;
    auto lp = (__attribute__((address_space(3))) void*)(uintptr_t)l;
    __builtin_amdgcn_global_load_lds(gp, lp, 16, 0, 0);
}

// ---------------------------------------------------------------------------
// LDS sub-tile unit (BK=64): row = 128 B = 8 chunks of 16 B. XOR swizzle:
// global chunk q of row r -> LDS chunk q^(r&7). One async16 covers 8 rows:
// lane l -> row +(l>>3), global chunk (l&7)^(l>>3). Reader k-half s reads
// chunk (s*4+quad)^(r&7). Conflict-free (SQ_LDS_BANK_CONFLICT=0, measured).
//
// R6: R5's 256^2 port kept the full __syncthreads() drain per K-tile — the
// exact anti-pattern T4 exists to remove (m218: drain0-8ph ~ 1ph) — at
// 1 block/CU with no co-resident overlap: proj 56->81 µs. REVERTED proj to
// the R4 m97 form. Counted-vmcnt applied instead where the drain stall is
// UNHIDDEN: exp/pv (2-resident regime, ~507 TF = m132's number). Per iter:
//   stage 8 loads (next tile, other buf) -> s_waitcnt vmcnt(8)  [oldest 8 =
//   current tile landed; per-wave count valid: each wave stages the strips
//   it later... strips are read cross-wave, but EVERY wave passes its own
//   vmcnt(8) before the barrier, so post-barrier all strips are landed]
//   -> raw s_barrier -> sched_barrier(0) -> ds_read+MFMA -> sched_barrier(0)
//   -> raw s_barrier  [protects buf^1 from next iter's overwrite].
// vmcnt(0) only at the last tile. pv's pre-loop rowsum gather is fenced with
// vmcnt(0) so its loads don't enter the count.
// ---------------------------------------------------------------------------

// Kernel 0: fp32 -> bf16 convert (x -> xb, [Wk;Wq;Wv] -> Wb). Grid-stride.
__global__ __launch_bounds__(256)
void convert_kernel(const float* __restrict__ x,  const float* __restrict__ Wk,
                    const float* __restrict__ Wq, const float* __restrict__ Wv,
                    unsigned short* __restrict__ xb, unsigned short* __restrict__ Wb)
{
    const long long total  = (long long)B_ * S_ * E_ + 3LL * D_ * E_;  // 11534336
    const long long stride = (long long)gridDim.x * 256 * 4;
    for (long long idx = ((long long)blockIdx.x * 256 + threadIdx.x) * 4;
         idx < total; idx += stride) {
        const float* src; unsigned short* dst; long long off;
        if (idx < (long long)B_ * S_ * E_) {
            src = x; dst = xb; off = idx;
        } else {
            long long w = idx - (long long)B_ * S_ * E_;
            const int sel = (int)(w >> 20);          // 2^20 elems per W
            off = w & 1048575LL;
            src = (sel == 0) ? Wk : (sel == 1) ? Wq : Wv;
            dst = Wb + ((long long)sel << 20);
        }
        const float4 f = *(const float4*)(src + off);
        ushort4 u = { f2bf(f.x), f2bf(f.y), f2bf(f.z), f2bf(f.w) };
        *(ushort4*)(dst + off) = u;
    }
}

// ---------------------------------------------------------------------------
// Kernel 1: projections (FROZEN — 916 TF m97 plateau, 4 blocks/CU implicit
// overlap; R5 proved the deep-pipeline port without counted waits is worse).
// C[m,n] = sum_e xb[m,e]*Wb[n,e]. Grid (64 m FAST, 24 ny).
// ---------------------------------------------------------------------------
__global__ __launch_bounds__(256, 4)
void proj_kernel(const unsigned short* __restrict__ xb,
                 const unsigned short* __restrict__ Wb,
                 unsigned short* __restrict__ Qb,
                 unsigned short* __restrict__ Kb,
                 unsigned short* __restrict__ Vt)
{
    __shared__ __align__(16) unsigned short As[128 * 64];
    __shared__ __align__(16) unsigned short Bs[128 * 64];

    const int t    = threadIdx.x;
    const int m0   = blockIdx.x * 128;
    const int ny   = blockIdx.y;
    const int wsel = ny >> 3;
    const int nloc = (ny & 7) * 128;

    const int lane = t & 63, wave = t >> 6;
    const int l15 = lane & 15, quad = lane >> 4;
    const int wm = wave & 1, wn = wave >> 1;
    const int sr = lane >> 3;
    const int sq = ((lane & 7) ^ sr) * 8;
    const int l7 = l15 & 7;
    const int rcA0 = (wm * 64 + l15) * 64 + ((quad ^ l7) * 8);
    const int rcA1 = (wm * 64 + l15) * 64 + (((4 + quad) ^ l7) * 8);
    const int rcB0 = (wn * 64 + l15) * 64 + ((quad ^ l7) * 8);
    const int rcB1 = (wn * 64 + l15) * 64 + (((4 + quad) ^ l7) * 8);

    const unsigned short* gA = xb + (size_t)(m0 + wave * 32 + sr) * E_ + sq;
    const unsigned short* gB = Wb + (size_t)(ny * 128 + wave * 32 + sr) * E_ + sq;
    unsigned short* lA = &As[wave * 2048];
    unsigned short* lB = &Bs[wave * 2048];

    f32x4 acc[4][4];
    #pragma unroll
    for (int i = 0; i < 4; i++)
        #pragma unroll
        for (int j = 0; j < 4; j++) acc[i][j] = {0.f, 0.f, 0.f, 0.f};

    for (int k0 = 0; k0 < E_; k0 += 64) {
        __syncthreads();
        #pragma unroll
        for (int i = 0; i < 4; i++) {
            async16(gA + k0 + i * 8 * E_, lA + i * 512);
            async16(gB + k0 + i * 8 * E_, lB + i * 512);
        }
        __syncthreads();

        #pragma unroll
        for (int s = 0; s < 2; s++) {
            bf16x8 af[4], bfr[4];
            const int ra = s ? rcA1 : rcA0, rb = s ? rcB1 : rcB0;
            #pragma unroll
            for (int i = 0; i < 4; i++) af[i]  = *(const bf16x8*)&As[ra + i * 1024];
            #pragma unroll
            for (int j = 0; j < 4; j++) bfr[j] = *(const bf16x8*)&Bs[rb + j * 1024];
            #pragma unroll
            for (int i = 0; i < 4; i++)
                #pragma unroll
                for (int j = 0; j < 4; j++)
                    acc[i][j] = __builtin_amdgcn_mfma_f32_16x16x32_bf16(af[i], bfr[j], acc[i][j], 0, 0, 0);
        }
    }

    if (wsel == 0) {
        #pragma unroll
        for (int i = 0; i < 4; i++)
            #pragma unroll
            for (int j = 0; j < 4; j++) {
                const int gn = nloc + wn * 64 + j * 16 + l15;
                #pragma unroll
                for (int r = 0; r < 4; r++) {
                    const int gm = m0 + wm * 64 + i * 16 + quad * 4 + r;
                    Kb[(size_t)gm * D_ + gn] = f2bf(acc[i][j][r]);
                }
            }
    } else if (wsel == 1) {
        #pragma unroll
        for (int i = 0; i < 4; i++)
            #pragma unroll
            for (int j = 0; j < 4; j++) {
                const int gn = nloc + wn * 64 + j * 16 + l15;
                #pragma unroll
                for (int r = 0; r < 4; r++) {
                    const int gm = m0 + wm * 64 + i * 16 + quad * 4 + r;
                    Qb[(size_t)gm * D_ + gn] = f2bf(acc[i][j][r] * 0.03125f);
                }
            }
    } else {
        #pragma unroll
        for (int i = 0; i < 4; i++)
            #pragma unroll
            for (int j = 0; j < 4; j++) {
                const int s0 = m0 + wm * 64 + i * 16 + quad * 4;
                const int b  = s0 >> 11, sl = s0 & (S_ - 1);
                const int gn = nloc + wn * 64 + j * 16 + l15;
                ushort4 u = { f2bf(acc[i][j][0]), f2bf(acc[i][j][1]),
                              f2bf(acc[i][j][2]), f2bf(acc[i][j][3]) };
                *(ushort4*)&Vt[((size_t)(b << 10) + gn) * S_ + sl] = u;
            }
    }
}

// ---------------------------------------------------------------------------
// Kernel 2: E = exp(Qs K^T), causal, bf16 -> P. 128x128 tile, BK=64,
// COUNTED-VMCNT double buffer (64 KB LDS, 2 blocks/CU). Compact 136-tile
// triangular grid, heavy-first. Scores bounded (|s| ~< 2).
// rowpart[b][nt*2+wn][row].
// ---------------------------------------------------------------------------
__global__ __launch_bounds__(256, 2)
void expscores_kernel(const unsigned short* __restrict__ Qb,
                      const unsigned short* __restrict__ Kb,
                      unsigned short* __restrict__ P,
                      float* __restrict__ rowpart)
{
    int rem = blockIdx.x;
    int mt = 15, cnt = 16;
    while (rem >= cnt) { rem -= cnt; mt--; cnt--; }
    const int nt = rem;
    const int b  = blockIdx.y;

    __shared__ __align__(16) unsigned short As[2 * 128 * 64];
    __shared__ __align__(16) unsigned short Bs[2 * 128 * 64];

    const int t = threadIdx.x;
    const int m0 = mt * 128, n0 = nt * 128;

    const int lane = t & 63, wave = t >> 6;
    const int l15 = lane & 15, quad = lane >> 4;
    const int wm = wave & 1, wn = wave >> 1;
    const int sr = lane >> 3;
    const int sq = ((lane & 7) ^ sr) * 8;
    const int l7 = l15 & 7;

    const unsigned short* gA = Qb + (size_t)b * S_ * D_ + (size_t)(m0 + wave * 32 + sr) * D_ + sq;
    const unsigned short* gB = Kb + (size_t)b * S_ * D_ + (size_t)(n0 + wave * 32 + sr) * D_ + sq;
    unsigned short* lA = &As[wave * 2048];
    unsigned short* lB = &Bs[wave * 2048];

    f32x4 acc[4][4];
    #pragma unroll
    for (int i = 0; i < 4; i++)
        #pragma unroll
        for (int j = 0; j < 4; j++) acc[i][j] = {0.f, 0.f, 0.f, 0.f};

    // prologue: tile 0 -> buf 0 (8 outstanding per wave)
    #pragma unroll
    for (int i = 0; i < 4; i++) {
        async16(gA + i * 8 * D_, lA + i * 512);
        async16(gB + i * 8 * D_, lB + i * 512);
    }

    for (int kt = 0; kt < 16; kt++) {
        const int cb = (kt & 1) * 8192;          // compute buffer
        const int nb = ((kt & 1) ^ 1) * 8192;    // stage buffer
        if (kt < 15) {
            const int k0 = (kt + 1) * 64;
            #pragma unroll
            for (int i = 0; i < 4; i++) {
                async16(gA + k0 + i * 8 * D_, lA + nb + i * 512);
                async16(gB + k0 + i * 8 * D_, lB + nb + i * 512);
            }
            asm volatile("s_waitcnt vmcnt(8)" ::: "memory");   // oldest 8 = tile kt landed
        } else {
            asm volatile("s_waitcnt vmcnt(0)" ::: "memory");
        }
        __builtin_amdgcn_s_barrier();            // all waves' tile-kt strips landed
        __builtin_amdgcn_sched_barrier(0);

        #pragma unroll
        for (int s = 0; s < 2; s++) {
            const int cs = ((s * 4 + quad) ^ l7) * 8;
            bf16x8 af[4], bfr[4];
            #pragma unroll
            for (int i = 0; i < 4; i++)
                af[i] = *(const bf16x8*)&As[cb + (wm * 64 + i * 16 + l15) * 64 + cs];
            #pragma unroll
            for (int j = 0; j < 4; j++)
                bfr[j] = *(const bf16x8*)&Bs[cb + (wn * 64 + j * 16 + l15) * 64 + cs];
            #pragma unroll
            for (int i = 0; i < 4; i++)
                #pragma unroll
                for (int j = 0; j < 4; j++)
                    acc[i][j] = __builtin_amdgcn_mfma_f32_16x16x32_bf16(af[i], bfr[j], acc[i][j], 0, 0, 0);
        }

        __builtin_amdgcn_sched_barrier(0);
        __builtin_amdgcn_s_barrier();            // buf cb reads done before next overwrite
    }

    unsigned short* Pb = P + (size_t)b * S_ * S_;
    #pragma unroll
    for (int i = 0; i < 4; i++)
        #pragma unroll
        for (int j = 0; j < 4; j++) {
            const int gn = n0 + wn * 64 + j * 16 + l15;
            #pragma unroll
            for (int r = 0; r < 4; r++) {
                const int gm = m0 + wm * 64 + i * 16 + quad * 4 + r;
                const float e = (gn <= gm) ? __expf(acc[i][j][r]) : 0.f;
                acc[i][j][r] = e;
                Pb[(size_t)gm * S_ + gn] = f2bf(e);
            }
        }

    float* rp = rowpart + ((size_t)b * 32 + nt * 2 + wn) * S_;
    #pragma unroll
    for (int i = 0; i < 4; i++) {
        float rsub[4];
        #pragma unroll
        for (int r = 0; r < 4; r++) {
            float s = acc[i][0][r] + acc[i][1][r] + acc[i][2][r] + acc[i][3][r];
            #pragma unroll
            for (int off = 8; off; off >>= 1) s += __shfl_xor(s, off);
            rsub[r] = s;
        }
        if (l15 == 0) {
            #pragma unroll
            for (int r = 0; r < 4; r++)
                rp[m0 + wm * 64 + i * 16 + quad * 4 + r] = rsub[r];
        }
    }
}

// ---------------------------------------------------------------------------
// Kernel 3: out = (E @ V) / rowsum. 128x128 tile, BK=64, COUNTED-VMCNT
// double buffer (64 KB LDS, 2 blocks/CU). Grid (8 nt FAST, 16 y, B);
// mt = (b&2)?y:15-y complementary resident pairing -> uniform 36 iters/CU.
// rowsum gather pre-loop, fenced with vmcnt(0) to keep the count clean.
// ---------------------------------------------------------------------------
__global__ __launch_bounds__(256, 2)
void pv_kernel(const unsigned short* __restrict__ P,
               const unsigned short* __restrict__ Vt,
               const float* __restrict__ rowpart,
               float* __restrict__ out)
{
    const int nt = blockIdx.x;
    const int yy = blockIdx.y;
    const int b  = blockIdx.z;
    const int mt = (b & 2) ? yy : (15 - yy);  // complementary pairing across b

    __shared__ __align__(16) unsigned short As[2 * 128 * 64];
    __shared__ __align__(16) unsigned short Bs[2 * 128 * 64];

    const int t = threadIdx.x;
    const int m0 = mt * 128, n0 = nt * 128;
    const int niter = 2 * mt + 2;             // kend = m0+128, BK=64

    const int lane = t & 63, wave = t >> 6;
    const int l15 = lane & 15, quad = lane >> 4;
    const int wm = wave & 1, wn = wave >> 1;
    const int sr = lane >> 3;
    const int sq = ((lane & 7) ^ sr) * 8;
    const int l7 = l15 & 7;

    const unsigned short* gA = P  + (size_t)b * S_ * S_ + (size_t)(m0 + wave * 32 + sr) * S_ + sq;
    const unsigned short* gB = Vt + (size_t)b * D_ * S_ + (size_t)(n0 + wave * 32 + sr) * S_ + sq;
    unsigned short* lA = &As[wave * 2048];
    unsigned short* lB = &Bs[wave * 2048];

    // 1/rowsum gather (rowpart ready at launch); fence so these loads don't
    // enter the counted-vmcnt bookkeeping below.
    const float* rp = rowpart + (size_t)b * 32 * S_ + (m0 + wm * 64 + lane);
    float rsum = 0.f;
    for (int k = 0; k < niter; k++) rsum += rp[(size_t)k * S_];
    const float invr = 1.0f / rsum;
    asm volatile("s_waitcnt vmcnt(0)" ::: "memory");

    f32x4 acc[4][4];
    #pragma unroll
    for (int i = 0; i < 4; i++)
        #pragma unroll
        for (int j = 0; j < 4; j++) acc[i][j] = {0.f, 0.f, 0.f, 0.f};

    // prologue: stage tile 0 into buffer 0 (8 outstanding per wave)
    #pragma unroll
    for (int i = 0; i < 4; i++) {
        async16(gA + i * 8 * S_, lA + i * 512);
        async16(gB + i * 8 * S_, lB + i * 512);
    }

    for (int kt = 0; kt < niter; kt++) {
        const int cb = (kt & 1) * 8192;
        const int nb = ((kt & 1) ^ 1) * 8192;
        if (kt + 1 < niter) {
            const int k0 = (kt + 1) * 64;
            #pragma unroll
            for (int i = 0; i < 4; i++) {
                async16(gA + k0 + i * 8 * S_, lA + nb + i * 512);
                async16(gB + k0 + i * 8 * S_, lB + nb + i * 512);
            }
            asm volatile("s_waitcnt vmcnt(8)" ::: "memory");
        } else {
            asm volatile("s_waitcnt vmcnt(0)" ::: "memory");
        }
        __builtin_amdgcn_s_barrier();
        __builtin_amdgcn_sched_barrier(0);

        #pragma unroll
        for (int s = 0; s < 2; s++) {
            const int cs = ((s * 4 + quad) ^ l7) * 8;
            bf16x8 af[4], bfr[4];
            #pragma unroll
            for (int i = 0; i < 4; i++)
                af[i] = *(const bf16x8*)&As[cb + (wm * 64 + i * 16 + l15) * 64 + cs];
            #pragma unroll
            for (int j = 0; j < 4; j++)
                bfr[j] = *(const bf16x8*)&Bs[cb + (wn * 64 + j * 16 + l15) * 64 + cs];
            #pragma unroll
            for (int i = 0; i < 4; i++)
                #pragma unroll
                for (int j = 0; j < 4; j++)
                    acc[i][j] = __builtin_amdgcn_mfma_f32_16x16x32_bf16(af[i], bfr[j], acc[i][j], 0, 0, 0);
        }

        __builtin_amdgcn_sched_barrier(0);
        __builtin_amdgcn_s_barrier();
    }

    #pragma unroll
    for (int i = 0; i < 4; i++) {
        #pragma unroll
        for (int r = 0; r < 4; r++) {
            const float vr = __shfl(invr, i * 16 + quad * 4 + r);
            const int gm = m0 + wm * 64 + i * 16 + quad * 4 + r;
            #pragma unroll
            for (int j = 0; j < 4; j++) {
                const int gn = n0 + wn * 64 + j * 16 + l15;
                out[((size_t)b * S_ + gm) * D_ + gn] = rintf(acc[i][j][r] * vr * 1e4f) * 1e-4f;
            }
        }
    }
}

// ---------------------------------------------------------------------------
// Workspace (~85 MB):
//   [0,     16.7M)  Qb bf16 [4][2048][1024]
//   [16.7M, 33.5M)  Kb bf16
//   [33.5M, 50.3M)  Vt bf16 [4][1024][2048]
//   [50.3M, 83.9M)  P  bf16 [4][2048][2048]
//       xb (16.7M) + Wb (6.3M) overlay the start of P's region (dead before
//       expscores writes P).
//   [83.9M, +1M)    rowpart fp32 [4][32][2048]
// ---------------------------------------------------------------------------
extern "C" void kernel_launch(void* const* d_in, const int* in_sizes, int n_in,
                              void* d_out, int out_size, void* d_ws, size_t ws_size,
                              hipStream_t stream)
{
    (void)in_sizes; (void)n_in; (void)out_size; (void)ws_size;
    const float* x  = (const float*)d_in[0];
    const float* Wk = (const float*)d_in[1];
    const float* Wq = (const float*)d_in[2];
    const float* Wv = (const float*)d_in[3];
    float* out = (float*)d_out;

    char* ws = (char*)d_ws;
    unsigned short* Qb = (unsigned short*)ws;
    unsigned short* Kb = Qb + (size_t)B_ * S_ * D_;
    unsigned short* Vt = Kb + (size_t)B_ * S_ * D_;
    unsigned short* P  = Vt + (size_t)B_ * D_ * S_;
    unsigned short* xb = P;                                  // overlay (dead early)
    unsigned short* Wb = xb + (size_t)B_ * S_ * E_;
    float* rowpart = (float*)(P + (size_t)B_ * S_ * S_);

    convert_kernel  <<<2048, 256, 0, stream>>>(x, Wk, Wq, Wv, xb, Wb);
    proj_kernel     <<<dim3(64, 24, 1),  256, 0, stream>>>(xb, Wb, Qb, Kb, Vt);
    expscores_kernel<<<dim3(136, B_, 1), 256, 0, stream>>>(Qb, Kb, P, rowpart);
    pv_kernel       <<<dim3(8, 16, B_),  256, 0, stream>>>(P, Vt, rowpart, out);
}